// Round 15
// baseline (47.897 us; speedup 1.0000x reference)
//
#include <hip/hip_runtime.h>

#define S_TOTAL (512 * 512)     // 262144
#define BATCH 64
#define NPR 32                  // partial rows (tc chunks)

typedef float vfloat4 __attribute__((ext_vector_type(4)));

// ds_swizzle xor helpers (imm must be literal). BitMode: (xor<<10)|0x1f.
__device__ __forceinline__ float swz_x1(float v) {
    return __int_as_float(__builtin_amdgcn_ds_swizzle(__float_as_int(v), 0x041F));
}
__device__ __forceinline__ float swz_x2(float v) {
    return __int_as_float(__builtin_amdgcn_ds_swizzle(__float_as_int(v), 0x081F));
}
__device__ __forceinline__ float swz_x4(float v) {
    return __int_as_float(__builtin_amdgcn_ds_swizzle(__float_as_int(v), 0x101F));
}
__device__ __forceinline__ float swz_x8(float v) {
    return __int_as_float(__builtin_amdgcn_ds_swizzle(__float_as_int(v), 0x201F));
}

// ---------------------------------------------------------------------------
// K1 (fused, k-split rebalance): block = (nr 0..19, tc 0..31) -> 640 blocks
// x 256 thr (4 waves).  Covers ty rows 4*tc..4*tc+3 (512 k) of ONE nr, ALL
// 64 batches (no duplicated fold work — R14's lesson).
//   phase 1: x-fold straight from global (proven 3-window pattern),
//            20-row y-window, zero-pad y outside [0,512) -> b1loc (10 KB)
//   phase 2: y-fold -> b2loc[512] (2 KB)  [proven tap/edge structure]
//   phase 3: wave wv handles batches 16*wv..16*wv+15; lane holds 2 k-quads;
//            R7-proven 16-value halving tree (+2 butterflies), lanes 0-15
//            store partial[tc][b*20+nr] with m = rev4(lane).
// XCD pinning: tc%8 == blk&7 (640 = 8*80, bijective) -> the 20 nr-blocks
// sharing a tc's 128 KB x-slice land on one XCD L2.
// ---------------------------------------------------------------------------
__global__ __launch_bounds__(256) void fused_za_kernel(
    const float* __restrict__ x,      // (64, 16384)
    const float* __restrict__ A,      // (20, 512, 512)
    float* __restrict__ partial)      // (32, 1280) elem b*20+nr
{
    __shared__ float b1loc[20][128];  // 10 KB
    __shared__ float b2loc[512];      // 2 KB

    const int t   = threadIdx.x;
    const int blk = blockIdx.x;
    // decode: xcd = blk&7, rest = blk>>3 (0..79)
    //   tc = (rest/20)*8 + xcd (0..31);  nr = rest%20
    const int rest = blk >> 3;
    const int tc   = (rest / 20) * 8 + (blk & 7);
    const int nr   = rest % 20;
    const int y0   = 16 * tc - 2;     // global y of local row 0

    const float* An = A + (size_t)nr * S_TOTAL;

    // ---- phase 1: x-fold (20 rows x 128 j), 10 iters/thread
    for (int i = t; i < 20 * 128; i += 256) {
        const int rl = i >> 7;
        const int j  = i & 127;
        const int y  = y0 + rl;
        float s = 0.0f;
        if (y >= 0 && y < 512) {
            const float* Ay = An + (size_t)y * 512;
            const int base = 4 * j;
            const vfloat4 m0 = *(const vfloat4*)(Ay + max(base - 4, 0));
            const vfloat4 m1 = *(const vfloat4*)(Ay + base);
            const vfloat4 m2 = *(const vfloat4*)(Ay + min(base + 4, 508));
            float e0 = m0.z, e1 = m0.w, e6 = m2.x, e7 = m2.y;
            if (j == 0)   { e0 = 0.0f; e1 = 0.0f; }
            if (j == 127) { e6 = 0.0f; e7 = 0.0f; }
            s = 0.125f * e0 + 0.375f * e1
              + 0.625f * m1.x + 0.875f * m1.y
              + 0.875f * m1.z + 0.625f * m1.w
              + 0.375f * e6 + 0.125f * e7;
            if (j == 0)   s += 0.375f * Ay[0]   + 0.125f * Ay[1];
            if (j == 127) s += 0.125f * Ay[510] + 0.375f * Ay[511];
        }
        b1loc[rl][j] = s;
    }
    __syncthreads();

    // ---- phase 2: y-fold (4 ty x 128 j) -> b2loc[kl = tyl*128 + j]
    const float w[8] = {0.125f, 0.375f, 0.625f, 0.875f,
                        0.875f, 0.625f, 0.375f, 0.125f};
#pragma unroll
    for (int i = t; i < 512; i += 256) {
        const int tyl = i >> 7;
        const int j   = i & 127;
        const int ty  = tc * 4 + tyl;
        float s = 0.0f;
#pragma unroll
        for (int p = 0; p < 8; ++p)
            s = fmaf(w[p], b1loc[4 * tyl + p][j], s);
        if (ty == 0)   s += 0.375f * b1loc[2][j]  + 0.125f * b1loc[3][j];   // y=0,1 (rl 2,3)
        if (ty == 127) s += 0.125f * b1loc[16][j] + 0.375f * b1loc[17][j];  // y=510,511 (rl 16,17)
        b2loc[i] = s;
    }
    __syncthreads();

    // ---- phase 3: dot with x. wave wv handles batches 16*wv..16*wv+15.
    const int wv   = t >> 6;
    const int lane = t & 63;
    const int b0   = wv * 16;
    const size_t xbase = (size_t)tc * 512 + 4 * lane;

    const vfloat4 bq0 = *(const vfloat4*)&b2loc[4 * lane];
    const vfloat4 bq1 = *(const vfloat4*)&b2loc[4 * lane + 256];

    float acc[16];
#pragma unroll
    for (int bi = 0; bi < 16; ++bi) {
        const float* xb = x + (size_t)(b0 + bi) * 16384 + xbase;
        const vfloat4 x0 = *(const vfloat4*)(xb);
        const vfloat4 x1 = *(const vfloat4*)(xb + 256);
        float a = 0.0f;
        a = fmaf(bq0.x, x0.x, fmaf(bq0.y, x0.y, fmaf(bq0.z, x0.z, fmaf(bq0.w, x0.w, a))));
        a = fmaf(bq1.x, x1.x, fmaf(bq1.y, x1.y, fmaf(bq1.z, x1.z, fmaf(bq1.w, x1.w, a))));
        acc[bi] = a;
    }

    // R7-proven 16-value halving tree over lane bits 0..3, butterflies 4..5
    const int lane1 = lane & 1, lane2 = lane & 2, lane4 = lane & 4, lane8 = lane & 8;
    float s1[8];
#pragma unroll
    for (int v = 0; v < 8; ++v) {
        const float u = acc[v], h = acc[v + 8];
        s1[v] = (lane1 ? h : u) + swz_x1(lane1 ? u : h);
    }
    float s2[4];
#pragma unroll
    for (int v = 0; v < 4; ++v) {
        const float u = s1[v], h = s1[v + 4];
        s2[v] = (lane2 ? h : u) + swz_x2(lane2 ? u : h);
    }
    float s3[2];
#pragma unroll
    for (int v = 0; v < 2; ++v) {
        const float u = s2[v], h = s2[v + 2];
        s3[v] = (lane4 ? h : u) + swz_x4(lane4 ? u : h);
    }
    float s4;
    {
        const float u = s3[0], h = s3[1];
        s4 = (lane8 ? h : u) + swz_x8(lane8 ? u : h);
    }
    s4 += __shfl_xor(s4, 16, 64);
    s4 += __shfl_xor(s4, 32, 64);

    // lanes 0-15 hold value m = rev4(lane)  (R5-R7 proven mapping)
    if (lane < 16) {
        const int m = ((lane & 1) << 3) | ((lane & 2) << 1) |
                      ((lane & 4) >> 1) | ((lane & 8) >> 3);
        partial[(size_t)tc * 1280 + (b0 + m) * 20 + nr] = s4;
    }
}

// ---------------------------------------------------------------------------
// K2: per-block 32-row za reduce (160 KB L2-hot, coalesced) + z recurrence +
// out = z*C^T + bias. 512 blocks = 256 s-chunks x 2 batch-halves; thread owns
// 4 consecutive s; float4 NT stores.  Structure unchanged (proven R12/R13).
// ---------------------------------------------------------------------------
__global__ __launch_bounds__(256) void out_kernel(
    const float* __restrict__ C,       // (S,4)
    const float* __restrict__ bias,    // (S,)
    const float* __restrict__ partial, // (32, 1280)
    float* __restrict__ out)           // (64,S)
{
    __shared__ float za_sh[1280];
    __shared__ float zs[256];
    const int t = threadIdx.x;

    const int sb = blockIdx.x >> 1;
    const int bh = blockIdx.x & 1;
    const int s0 = (sb * 256 + t) * 4;
    const vfloat4 c0 = *(const vfloat4*)(C + (size_t)s0 * 4);
    const vfloat4 c1 = *(const vfloat4*)(C + (size_t)s0 * 4 + 4);
    const vfloat4 c2 = *(const vfloat4*)(C + (size_t)s0 * 4 + 8);
    const vfloat4 c3 = *(const vfloat4*)(C + (size_t)s0 * 4 + 12);
    const vfloat4 bv = *(const vfloat4*)(bias + s0);

#pragma unroll
    for (int qq = 0; qq < 5; ++qq) {
        const int c = qq * 256 + t;
        float a0 = 0, a1 = 0, a2 = 0, a3 = 0;
#pragma unroll
        for (int r = 0; r < NPR; r += 4) {
            a0 += partial[(size_t)(r + 0) * 1280 + c];
            a1 += partial[(size_t)(r + 1) * 1280 + c];
            a2 += partial[(size_t)(r + 2) * 1280 + c];
            a3 += partial[(size_t)(r + 3) * 1280 + c];
        }
        za_sh[c] = (a0 + a1) + (a2 + a3);
    }
    __syncthreads();
    if (t < 64) {
#pragma unroll
        for (int r = 0; r < 4; ++r) {
            float zv = za_sh[t * 20 + r];               // n = 0
#pragma unroll
            for (int n = 1; n < 5; ++n)
                zv *= (1.0f + za_sh[t * 20 + n * 4 + r]);
            zs[t * 4 + r] = zv;
        }
    }
    __syncthreads();

#pragma unroll 8
    for (int bb = bh * 32; bb < bh * 32 + 32; ++bb) {
        const float z0 = zs[bb * 4 + 0], z1 = zs[bb * 4 + 1];
        const float z2 = zs[bb * 4 + 2], z3 = zs[bb * 4 + 3];
        vfloat4 o;
        o.x = fmaf(z0, c0.x, fmaf(z1, c0.y, fmaf(z2, c0.z, fmaf(z3, c0.w, bv.x))));
        o.y = fmaf(z0, c1.x, fmaf(z1, c1.y, fmaf(z2, c1.z, fmaf(z3, c1.w, bv.y))));
        o.z = fmaf(z0, c2.x, fmaf(z1, c2.y, fmaf(z2, c2.z, fmaf(z3, c2.w, bv.z))));
        o.w = fmaf(z0, c3.x, fmaf(z1, c3.y, fmaf(z2, c3.z, fmaf(z3, c3.w, bv.w))));
        __builtin_nontemporal_store(o, (vfloat4*)(out + (size_t)bb * S_TOTAL + s0));
    }
}

// ---------------------------------------------------------------------------
extern "C" void kernel_launch(void* const* d_in, const int* in_sizes, int n_in,
                              void* d_out, int out_size, void* d_ws, size_t ws_size,
                              hipStream_t stream)
{
    const float* x    = (const float*)d_in[0];
    const float* A    = (const float*)d_in[1];
    const float* C    = (const float*)d_in[2];
    const float* bias = (const float*)d_in[3];
    float* out = (float*)d_out;

    float* partial = (float*)d_ws;                        // 32*1280 = 160 KB

    fused_za_kernel<<<640, 256, 0, stream>>>(x, A, partial);
    out_kernel<<<512, 256, 0, stream>>>(C, bias, partial, out);
}

// Round 16
// 30.912 us; speedup vs baseline: 1.5495x; 1.5495x over previous
//
#include <hip/hip_runtime.h>

#define S_TOTAL (512 * 512)     // 262144
#define BATCH 64
#define NPR 16                  // partial rows (tcp chunks)

typedef float vfloat4 __attribute__((ext_vector_type(4)));

// ds_swizzle xor helpers (imm must be literal). BitMode: (xor<<10)|0x1f.
__device__ __forceinline__ float swz_x1(float v) {
    return __int_as_float(__builtin_amdgcn_ds_swizzle(__float_as_int(v), 0x041F));
}
__device__ __forceinline__ float swz_x2(float v) {
    return __int_as_float(__builtin_amdgcn_ds_swizzle(__float_as_int(v), 0x081F));
}
__device__ __forceinline__ float swz_x4(float v) {
    return __int_as_float(__builtin_amdgcn_ds_swizzle(__float_as_int(v), 0x101F));
}
__device__ __forceinline__ float swz_x8(float v) {
    return __int_as_float(__builtin_amdgcn_ds_swizzle(__float_as_int(v), 0x201F));
}

// ---------------------------------------------------------------------------
// K1 (fused, lean — R13 proven best): block = (nr 0..19, tcp 0..15).
// Covers ty rows 8*tcp..8*tcp+7 (1024 k) of ONE nr, all 64 batches.
//   phase 1: x-fold straight from global (3-window pattern), 36-row y-window,
//            zero-pad y outside [0,512)  -> b1loc (18 KB)
//   phase 2: y-fold -> b2loc[1024] (4 KB)
//   phase 3: dot with x (8 waves x 8 batches, 4 k-quads/lane), 3-stage
//            halving tree + 3 butterflies -> partial[tcp][b*20+nr]
// XCD-pinned: tcp%8 == blk%8 (320 = 8*40, bijective).
// ---------------------------------------------------------------------------
__global__ __launch_bounds__(512) void fused_za_kernel(
    const float* __restrict__ x,      // (64, 16384)
    const float* __restrict__ A,      // (20, 512, 512)
    float* __restrict__ partial)      // (16, 1280) elem b*20+nr
{
    __shared__ float b1loc[36][128];  // 18 KB
    __shared__ float b2loc[1024];     // 4 KB

    const int t   = threadIdx.x;
    const int blk = blockIdx.x;
    // XCD-pinned decode: tcp = (q/20)*8 + (blk&7), nr = q%20, q = blk>>3
    const int q   = blk >> 3;
    const int nr  = q % 20;
    const int tcp = (q / 20) * 8 + (blk & 7);
    const int y0  = 32 * tcp - 2;     // global y of local row 0

    const float* An = A + (size_t)nr * S_TOTAL;

    // ---- phase 1: x-fold (36 rows x 128 j)
#pragma unroll 3
    for (int i = t; i < 36 * 128; i += 512) {
        const int rl = i >> 7;
        const int j  = i & 127;
        const int y  = y0 + rl;
        float s = 0.0f;
        if (y >= 0 && y < 512) {
            const float* Ay = An + (size_t)y * 512;
            const int base = 4 * j;
            const vfloat4 m0 = *(const vfloat4*)(Ay + max(base - 4, 0));
            const vfloat4 m1 = *(const vfloat4*)(Ay + base);
            const vfloat4 m2 = *(const vfloat4*)(Ay + min(base + 4, 508));
            float e0 = m0.z, e1 = m0.w, e6 = m2.x, e7 = m2.y;
            if (j == 0)   { e0 = 0.0f; e1 = 0.0f; }
            if (j == 127) { e6 = 0.0f; e7 = 0.0f; }
            s = 0.125f * e0 + 0.375f * e1
              + 0.625f * m1.x + 0.875f * m1.y
              + 0.875f * m1.z + 0.625f * m1.w
              + 0.375f * e6 + 0.125f * e7;
            if (j == 0)   s += 0.375f * Ay[0]   + 0.125f * Ay[1];
            if (j == 127) s += 0.125f * Ay[510] + 0.375f * Ay[511];
        }
        b1loc[rl][j] = s;
    }
    __syncthreads();

    // ---- phase 2: y-fold (8 ty x 128 j) -> b2loc[kl = tyl*128 + j]
    const float w[8] = {0.125f, 0.375f, 0.625f, 0.875f,
                        0.875f, 0.625f, 0.375f, 0.125f};
#pragma unroll
    for (int i = t; i < 1024; i += 512) {
        const int tyl = i >> 7;
        const int j   = i & 127;
        const int ty  = tcp * 8 + tyl;
        float s = 0.0f;
#pragma unroll
        for (int p = 0; p < 8; ++p)
            s = fmaf(w[p], b1loc[4 * tyl + p][j], s);
        if (ty == 0)   s += 0.375f * b1loc[2][j]  + 0.125f * b1loc[3][j];   // y=0,1 (rl 2,3)
        if (ty == 127) s += 0.125f * b1loc[32][j] + 0.375f * b1loc[33][j];  // y=510,511 (rl 32,33)
        b2loc[i] = s;
    }
    __syncthreads();

    // ---- phase 3: dot with x.  wave wv handles batches 8*wv..8*wv+7.
    const int wv   = t >> 6;
    const int lane = t & 63;
    const int b0   = wv * 8;
    const size_t xbase = (size_t)tcp * 1024 + 4 * lane;

    // b2 quads (LDS, conflict-free b128)
    vfloat4 bq0 = *(const vfloat4*)&b2loc[4 * lane];
    vfloat4 bq1 = *(const vfloat4*)&b2loc[4 * lane + 256];
    vfloat4 bq2 = *(const vfloat4*)&b2loc[4 * lane + 512];
    vfloat4 bq3 = *(const vfloat4*)&b2loc[4 * lane + 768];

    float acc[8];
#pragma unroll
    for (int bi = 0; bi < 8; ++bi) {
        const float* xb = x + (size_t)(b0 + bi) * 16384 + xbase;
        const vfloat4 x0 = *(const vfloat4*)(xb);
        const vfloat4 x1 = *(const vfloat4*)(xb + 256);
        const vfloat4 x2 = *(const vfloat4*)(xb + 512);
        const vfloat4 x3 = *(const vfloat4*)(xb + 768);
        float a = 0.0f;
        a = fmaf(bq0.x, x0.x, fmaf(bq0.y, x0.y, fmaf(bq0.z, x0.z, fmaf(bq0.w, x0.w, a))));
        a = fmaf(bq1.x, x1.x, fmaf(bq1.y, x1.y, fmaf(bq1.z, x1.z, fmaf(bq1.w, x1.w, a))));
        a = fmaf(bq2.x, x2.x, fmaf(bq2.y, x2.y, fmaf(bq2.z, x2.z, fmaf(bq2.w, x2.w, a))));
        a = fmaf(bq3.x, x3.x, fmaf(bq3.y, x3.y, fmaf(bq3.z, x3.z, fmaf(bq3.w, x3.w, a))));
        acc[bi] = a;
    }

    // halving tree: 8 values over lane bits 0..2, butterfly bits 3..5
    const int lane1 = lane & 1, lane2 = lane & 2, lane4 = lane & 4;
    float s1[4];
#pragma unroll
    for (int v = 0; v < 4; ++v) {
        const float u = acc[v], h = acc[v + 4];
        s1[v] = (lane1 ? h : u) + swz_x1(lane1 ? u : h);
    }
    float s2[2];
#pragma unroll
    for (int v = 0; v < 2; ++v) {
        const float u = s1[v], h = s1[v + 2];
        s2[v] = (lane2 ? h : u) + swz_x2(lane2 ? u : h);
    }
    float s3;
    {
        const float u = s2[0], h = s2[1];
        s3 = (lane4 ? h : u) + swz_x4(lane4 ? u : h);
    }
    s3 += swz_x8(s3);
    s3 += __shfl_xor(s3, 16, 64);
    s3 += __shfl_xor(s3, 32, 64);

    // lanes 0-7 hold value m = rev3(lane): bit2=lane0, bit1=lane1, bit0=lane2
    if (lane < 8) {
        const int m = ((lane & 1) << 2) | (lane & 2) | ((lane & 4) >> 2);
        partial[(size_t)tcp * 1280 + (b0 + m) * 20 + nr] = s3;
    }
}

// ---------------------------------------------------------------------------
// K2: per-block 16-row za reduce (80 KB L2-hot, coalesced) + z recurrence +
// out = z*C^T + bias. 512 blocks = 256 s-chunks x 2 batch-halves; thread owns
// 4 consecutive s; float4 NT stores.  Unchanged from R12/R13 (proven).
// ---------------------------------------------------------------------------
__global__ __launch_bounds__(256) void out_kernel(
    const float* __restrict__ C,       // (S,4)
    const float* __restrict__ bias,    // (S,)
    const float* __restrict__ partial, // (16, 1280)
    float* __restrict__ out)           // (64,S)
{
    __shared__ float za_sh[1280];
    __shared__ float zs[256];
    const int t = threadIdx.x;

    const int sb = blockIdx.x >> 1;
    const int bh = blockIdx.x & 1;
    const int s0 = (sb * 256 + t) * 4;
    const vfloat4 c0 = *(const vfloat4*)(C + (size_t)s0 * 4);
    const vfloat4 c1 = *(const vfloat4*)(C + (size_t)s0 * 4 + 4);
    const vfloat4 c2 = *(const vfloat4*)(C + (size_t)s0 * 4 + 8);
    const vfloat4 c3 = *(const vfloat4*)(C + (size_t)s0 * 4 + 12);
    const vfloat4 bv = *(const vfloat4*)(bias + s0);

#pragma unroll
    for (int qq = 0; qq < 5; ++qq) {
        const int c = qq * 256 + t;
        float a0 = 0, a1 = 0, a2 = 0, a3 = 0;
#pragma unroll
        for (int r = 0; r < NPR; r += 4) {
            a0 += partial[(size_t)(r + 0) * 1280 + c];
            a1 += partial[(size_t)(r + 1) * 1280 + c];
            a2 += partial[(size_t)(r + 2) * 1280 + c];
            a3 += partial[(size_t)(r + 3) * 1280 + c];
        }
        za_sh[c] = (a0 + a1) + (a2 + a3);
    }
    __syncthreads();
    if (t < 64) {
#pragma unroll
        for (int r = 0; r < 4; ++r) {
            float zv = za_sh[t * 20 + r];               // n = 0
#pragma unroll
            for (int n = 1; n < 5; ++n)
                zv *= (1.0f + za_sh[t * 20 + n * 4 + r]);
            zs[t * 4 + r] = zv;
        }
    }
    __syncthreads();

#pragma unroll 8
    for (int bb = bh * 32; bb < bh * 32 + 32; ++bb) {
        const float z0 = zs[bb * 4 + 0], z1 = zs[bb * 4 + 1];
        const float z2 = zs[bb * 4 + 2], z3 = zs[bb * 4 + 3];
        vfloat4 o;
        o.x = fmaf(z0, c0.x, fmaf(z1, c0.y, fmaf(z2, c0.z, fmaf(z3, c0.w, bv.x))));
        o.y = fmaf(z0, c1.x, fmaf(z1, c1.y, fmaf(z2, c1.z, fmaf(z3, c1.w, bv.y))));
        o.z = fmaf(z0, c2.x, fmaf(z1, c2.y, fmaf(z2, c2.z, fmaf(z3, c2.w, bv.z))));
        o.w = fmaf(z0, c3.x, fmaf(z1, c3.y, fmaf(z2, c3.z, fmaf(z3, c3.w, bv.w))));
        __builtin_nontemporal_store(o, (vfloat4*)(out + (size_t)bb * S_TOTAL + s0));
    }
}

// ---------------------------------------------------------------------------
extern "C" void kernel_launch(void* const* d_in, const int* in_sizes, int n_in,
                              void* d_out, int out_size, void* d_ws, size_t ws_size,
                              hipStream_t stream)
{
    const float* x    = (const float*)d_in[0];
    const float* A    = (const float*)d_in[1];
    const float* C    = (const float*)d_in[2];
    const float* bias = (const float*)d_in[3];
    float* out = (float*)d_out;

    float* partial = (float*)d_ws;                        // 16*1280 = 80 KB

    fused_za_kernel<<<320, 512, 0, stream>>>(x, A, partial);
    out_kernel<<<512, 256, 0, stream>>>(C, bias, partial, out);
}